// Round 7
// baseline (215.094 us; speedup 1.0000x reference)
//
#include <hip/hip_runtime.h>
#include <math.h>

#define B 8
#define L 4096
#define D 64
#define TD 128          // 2*D
#define G 64
#define KS 16
#define NSLOT 1024      // G*KS
#define EPS 1e-5f
#define MARGIN 0.015f

// ---- workspace layout (float offsets) ----
#define OFF_PART 0        // 8192 fp32 ssum partials [b][c][d], c = 16 chunks of 64 slots
#define OFF_WGT  8192     // 8192 fp32 [k][g] 128x64   (exact recompute)
#define OFF_WST  16384    // 2048 fp32 [k][s] 128x16   (exact recompute)
#define OFF_MW0B 18432    // 16384 bf16 (8192 f)  MFMA B-frag
#define OFF_MW1B 26624    // 8192 bf16 (4096 f)
#define OFF_GW0B 30720    // 8192 bf16 (4096 f)
#define OFF_WGB  34816    // 8192 bf16 (4096 f)
#define OFF_WSB  38912    // 2048 bf16 (1024 f)
#define OFF_UW0B 39936    // 16384 bf16 (8192 f)
#define OFF_UW1B 48128    // 8192 bf16 (4096 f)
#define OFF_INC  52224    // 524288 fp32 incoming [B][N][D]
// total 576512 floats ≈ 2.31 MB

typedef __attribute__((ext_vector_type(8))) short short8;
typedef __attribute__((ext_vector_type(4))) float f32x4;

__device__ __forceinline__ float gelu_exact(float x) {
    return 0.5f * x * (1.0f + erff(x * 0.70710678118654752f));
}

__device__ __forceinline__ unsigned short f2bf(float f) {
    unsigned u = __float_as_uint(f);
    u += 0x7FFFu + ((u >> 16) & 1u);        // round-to-nearest-even
    return (unsigned short)(u >> 16);
}

__device__ __forceinline__ float bf2f(unsigned short u) {
    unsigned v = ((unsigned)u) << 16;
    return __uint_as_float(v);
}

// B-fragment mapping for 16x16x32 bf16 MFMA, 16-col tiles, K=128.
__device__ __forceinline__ void fragmap(int r, int& j, int& k) {
    int e = r & 7, l = (r >> 3) & 63, ks = (r >> 9) & 3, jt = r >> 11;
    j = jt * 16 + (l & 15);
    k = ks * 32 + (l >> 4) * 8 + e;
}

// ---------------- prep: weight packs + ssum partials ----------------
__global__ __launch_bounds__(256) void prep_kernel(
    const float* __restrict__ S, const float* __restrict__ Wg,
    const float* __restrict__ Ws, const float* __restrict__ mw0,
    const float* __restrict__ mw1, const float* __restrict__ gw0,
    const float* __restrict__ uw0, const float* __restrict__ uw1,
    float* __restrict__ ws)
{
    int blk = blockIdx.x;
    if (blk < 304) {
        int idx = blk * 256 + threadIdx.x;   // [0, 77824)
        unsigned short* wsu = (unsigned short*)ws;
        int j, k;
        if (idx < 8192) {                        // WGT fp32 [k][g]
            int kk = idx >> 6, g = idx & 63;
            ws[OFF_WGT + idx] = Wg[g * TD + kk];
        } else if (idx < 10240) {                // WST fp32 [k][s]
            int r = idx - 8192; int kk = r >> 4, s = r & 15;
            ws[OFF_WST + r] = Ws[s * TD + kk];
        } else if (idx < 26624) {                // MW0B
            int r = idx - 10240; fragmap(r, j, k);
            wsu[OFF_MW0B * 2 + r] = f2bf(mw0[j * TD + k]);
        } else if (idx < 34816) {                // MW1B
            int r = idx - 26624; fragmap(r, j, k);
            wsu[OFF_MW1B * 2 + r] = f2bf(mw1[j * TD + k]);
        } else if (idx < 43008) {                // GW0B
            int r = idx - 34816; fragmap(r, j, k);
            wsu[OFF_GW0B * 2 + r] = f2bf(gw0[j * TD + k]);
        } else if (idx < 51200) {                // WGB
            int r = idx - 43008; fragmap(r, j, k);
            wsu[OFF_WGB * 2 + r] = f2bf(Wg[j * TD + k]);
        } else if (idx < 53248) {                // WSB (16 cols)
            int r = idx - 51200; fragmap(r, j, k);
            wsu[OFF_WSB * 2 + r] = f2bf(Ws[j * TD + k]);
        } else if (idx < 69632) {                // UW0B
            int r = idx - 53248; fragmap(r, j, k);
            wsu[OFF_UW0B * 2 + r] = f2bf(uw0[j * TD + k]);
        } else if (idx < 77824) {                // UW1B
            int r = idx - 69632; fragmap(r, j, k);
            wsu[OFF_UW1B * 2 + r] = f2bf(uw1[j * TD + k]);
        }
    } else {
        // ssum partials: block per (b, chunk of 64 slots); serial in-chunk order
        int pb = blk - 304;              // [0,128)
        int b = pb >> 4, c = pb & 15;
        int d = threadIdx.x;
        if (d < D) {
            const float* Sp = S + ((size_t)(b * NSLOT + c * 64)) * D + d;
            float acc = 0.f;
            #pragma unroll 16
            for (int u = 0; u < 64; ++u) acc += Sp[(size_t)u * D];
            ws[OFF_PART + pb * 64 + d] = acc;
        }
    }
}

// ---------------- fused token kernel: routing + MLPs + gate + scatter ----------------
__global__ __launch_bounds__(256) void token_kernel(
    const float* __restrict__ X,
    const float* __restrict__ mb0, const float* __restrict__ mb1,
    const float* __restrict__ gb0, const float* __restrict__ gw1,
    const float* __restrict__ gb1, float* __restrict__ ws)
{
    __shared__ __align__(16) unsigned short xsl[64 * 136];   // bf16 XS tile
    __shared__ __align__(16) char uni[64 * 85 * 4];          // lgl f32[64][85] -> hhl u16[64*136]
    __shared__ float msgl[64 * 68];
    __shared__ __align__(16) unsigned short ghl[64 * 72];    // bf16 gate hidden
    __shared__ float ssf[64];
    __shared__ float gatel[64];
    __shared__ int   slotl[64];
    __shared__ int   flist[64];
    __shared__ int   flagcnt;

    float (*lgl)[85] = (float(*)[85])uni;
    unsigned short* hhl = (unsigned short*)uni;

    const int tid  = threadIdx.x;
    const int tok0 = blockIdx.x * 64;
    const int b    = tok0 >> 12;      // / L

    if (tid == 0) flagcnt = 0;
    // ---- ssum from partials (fixed chunk order -> deterministic) ----
    if (tid < 64) {
        float a = 0.f;
        #pragma unroll
        for (int c = 0; c < 16; ++c) a += ws[OFF_PART + (b * 16 + c) * 64 + tid];
        ssf[tid] = a * (1.0f / NSLOT);
    }
    __syncthreads();

    // ---- stage XS as bf16 ----
    {
        int t = tid >> 2, q = tid & 3;
        unsigned short tmp[32];
        if (q < 2) {
            const float* Xp = X + (size_t)(tok0 + t) * D + q * 32;
            #pragma unroll
            for (int u = 0; u < 8; ++u) {
                float4 v = *(const float4*)(Xp + u * 4);
                tmp[u*4+0] = f2bf(v.x); tmp[u*4+1] = f2bf(v.y);
                tmp[u*4+2] = f2bf(v.z); tmp[u*4+3] = f2bf(v.w);
            }
        } else {
            const float* Sp = ssf + (q - 2) * 32;
            #pragma unroll
            for (int u = 0; u < 32; ++u) tmp[u] = f2bf(Sp[u]);
        }
        #pragma unroll
        for (int s = 0; s < 4; ++s)
            *(short8*)&xsl[t * 136 + (q * 4 + s) * 8] = *(const short8*)&tmp[s * 8];
    }
    __syncthreads();

    const int w  = tid >> 6;
    const int l  = tid & 63;
    const int lr = l & 15;
    const int lk = l >> 4;
    const unsigned short* wsu = (const unsigned short*)ws;

    // ---- routing logits via MFMA ----
    if (w < 2) {          // group logits: wave w -> col-tiles {2w, 2w+1}
        f32x4 acc[2][4];
        #pragma unroll
        for (int c2 = 0; c2 < 2; ++c2)
            #pragma unroll
            for (int tt = 0; tt < 4; ++tt) acc[c2][tt] = (f32x4){0.f,0.f,0.f,0.f};
        for (int ks = 0; ks < 4; ++ks) {
            short8 a[4];
            #pragma unroll
            for (int tt = 0; tt < 4; ++tt)
                a[tt] = *(const short8*)&xsl[(tt * 16 + lr) * 136 + (ks * 4 + lk) * 8];
            #pragma unroll
            for (int c2 = 0; c2 < 2; ++c2) {
                int jt = w * 2 + c2;
                short8 bb = *(const short8*)&wsu[OFF_WGB * 2 + ((jt * 4 + ks) * 64 + l) * 8];
                #pragma unroll
                for (int tt = 0; tt < 4; ++tt)
                    acc[c2][tt] = __builtin_amdgcn_mfma_f32_16x16x32_bf16(a[tt], bb, acc[c2][tt], 0, 0, 0);
            }
        }
        #pragma unroll
        for (int c2 = 0; c2 < 2; ++c2) {
            int j = (w * 2 + c2) * 16 + lr;
            #pragma unroll
            for (int tt = 0; tt < 4; ++tt)
                #pragma unroll
                for (int r = 0; r < 4; ++r)
                    lgl[tt * 16 + lk * 4 + r][j] = acc[c2][tt][r];
        }
    } else {              // slot logits: waves 2,3 split token-tiles
        f32x4 acc[2];
        acc[0] = (f32x4){0.f,0.f,0.f,0.f}; acc[1] = (f32x4){0.f,0.f,0.f,0.f};
        int ttb = (w - 2) * 2;
        for (int ks = 0; ks < 4; ++ks) {
            short8 a0 = *(const short8*)&xsl[((ttb    ) * 16 + lr) * 136 + (ks * 4 + lk) * 8];
            short8 a1 = *(const short8*)&xsl[((ttb + 1) * 16 + lr) * 136 + (ks * 4 + lk) * 8];
            short8 bb = *(const short8*)&wsu[OFF_WSB * 2 + (ks * 64 + l) * 8];
            acc[0] = __builtin_amdgcn_mfma_f32_16x16x32_bf16(a0, bb, acc[0], 0, 0, 0);
            acc[1] = __builtin_amdgcn_mfma_f32_16x16x32_bf16(a1, bb, acc[1], 0, 0, 0);
        }
        #pragma unroll
        for (int tt2 = 0; tt2 < 2; ++tt2)
            #pragma unroll
            for (int r = 0; r < 4; ++r)
                lgl[(ttb + tt2) * 16 + lk * 4 + r][64 + lr] = acc[tt2][r];
    }
    __syncthreads();

    // ---- per-token argmax + top-2 gap flag ----
    if (tid < 64) {
        int t = tid;
        float bv = lgl[t][0], g2 = -1e30f; int bg = 0;
        for (int g = 1; g < G; ++g) {
            float v = lgl[t][g];
            if (v > bv) { g2 = bv; bv = v; bg = g; } else if (v > g2) g2 = v;
        }
        float sv = lgl[t][64], s2 = -1e30f; int bs = 0;
        for (int s = 1; s < KS; ++s) {
            float v = lgl[t][64 + s];
            if (v > sv) { s2 = sv; sv = v; bs = s; } else if (v > s2) s2 = v;
        }
        slotl[t] = bg * KS + bs;
        if ((bv - g2 < MARGIN) || (sv - s2 < MARGIN)) {
            int i = atomicAdd(&flagcnt, 1); flist[i] = t;
        }
    }
    __syncthreads();

    // ---- exact fp32 recompute for flagged tokens: one wave per token, no barriers ----
    {
        int nf = flagcnt;
        for (int fi = w; fi < nf; fi += 4) {
            int t = flist[fi];
            const float* xp = X + (size_t)(tok0 + t) * D;
            float a1 = 0.f, a2 = 0.f;
            #pragma unroll 8
            for (int k = 0; k < 64; ++k) {
                float xk = xp[k];
                a1 += ws[OFF_WGT + k * G + l] * xk;
                if (l < KS) a2 += ws[OFF_WST + k * KS + l] * xk;
            }
            #pragma unroll 8
            for (int k = 0; k < 64; ++k) {
                float xk = ssf[k];
                a1 += ws[OFF_WGT + (64 + k) * G + l] * xk;
                if (l < KS) a2 += ws[OFF_WST + (64 + k) * KS + l] * xk;
            }
            // wave argmax over 64 group logits (first-max: ties -> smaller index)
            float v = a1; int idx = l;
            #pragma unroll
            for (int off = 32; off >= 1; off >>= 1) {
                float vo = __shfl_xor(v, off, 64);
                int   io = __shfl_xor(idx, off, 64);
                if (vo > v || (vo == v && io < idx)) { v = vo; idx = io; }
            }
            int bg = idx;
            // argmax over 16 slot logits (lanes 0..15; xor<=8 stays in 16-group)
            float v2 = (l < KS) ? a2 : -1e30f; int i2 = (l < KS) ? l : 1000;
            #pragma unroll
            for (int off = 8; off >= 1; off >>= 1) {
                float vo = __shfl_xor(v2, off, 64);
                int   io = __shfl_xor(i2, off, 64);
                if (vo > v2 || (vo == v2 && io < i2)) { v2 = vo; i2 = io; }
            }
            if (l == 0) slotl[t] = bg * KS + i2;
        }
    }
    __syncthreads();   // also: last read of lgl done; uni becomes hhl

    // ---- GEMM1: H = gelu(XS @ mw0^T + mb0) ----
    {
        f32x4 acc[2][4];
        #pragma unroll
        for (int a_ = 0; a_ < 2; ++a_)
            #pragma unroll
            for (int b_ = 0; b_ < 4; ++b_) acc[a_][b_] = (f32x4){0.f, 0.f, 0.f, 0.f};

        for (int ks = 0; ks < 4; ++ks) {
            short8 a[4];
            #pragma unroll
            for (int tt = 0; tt < 4; ++tt)
                a[tt] = *(const short8*)&xsl[(tt * 16 + lr) * 136 + (ks * 4 + lk) * 8];
            #pragma unroll
            for (int jt2 = 0; jt2 < 2; ++jt2) {
                int jt = w * 2 + jt2;
                short8 bb = *(const short8*)&wsu[OFF_MW0B * 2 + ((jt * 4 + ks) * 64 + l) * 8];
                #pragma unroll
                for (int tt = 0; tt < 4; ++tt)
                    acc[jt2][tt] = __builtin_amdgcn_mfma_f32_16x16x32_bf16(a[tt], bb, acc[jt2][tt], 0, 0, 0);
            }
        }
        __syncthreads();   // ensure all lgl reads finished before overwriting uni (recompute done above)
        #pragma unroll
        for (int jt2 = 0; jt2 < 2; ++jt2) {
            int j = w * 32 + jt2 * 16 + lr;
            float bias = mb0[j];
            #pragma unroll
            for (int tt = 0; tt < 4; ++tt) {
                #pragma unroll
                for (int r = 0; r < 4; ++r) {
                    int t = tt * 16 + lk * 4 + r;
                    hhl[t * 136 + j] = f2bf(gelu_exact(acc[jt2][tt][r] + bias));
                }
            }
        }
    }
    __syncthreads();

    // ---- GEMM2: waves 0,1: msg = H @ mw1^T ; waves 2,3: gh = gelu(XS @ gw0^T) ----
    {
        f32x4 acc[2][4];
        #pragma unroll
        for (int a_ = 0; a_ < 2; ++a_)
            #pragma unroll
            for (int b_ = 0; b_ < 4; ++b_) acc[a_][b_] = (f32x4){0.f, 0.f, 0.f, 0.f};

        const unsigned short* srcA = (w < 2) ? hhl : xsl;
        const int wb   = (w < 2) ? w : (w - 2);
        const int boff = (w < 2) ? OFF_MW1B * 2 : OFF_GW0B * 2;

        for (int ks = 0; ks < 4; ++ks) {
            short8 a[4];
            #pragma unroll
            for (int tt = 0; tt < 4; ++tt)
                a[tt] = *(const short8*)&srcA[(tt * 16 + lr) * 136 + (ks * 4 + lk) * 8];
            #pragma unroll
            for (int jt2 = 0; jt2 < 2; ++jt2) {
                int jt = wb * 2 + jt2;
                short8 bb = *(const short8*)&wsu[boff + ((jt * 4 + ks) * 64 + l) * 8];
                #pragma unroll
                for (int tt = 0; tt < 4; ++tt)
                    acc[jt2][tt] = __builtin_amdgcn_mfma_f32_16x16x32_bf16(a[tt], bb, acc[jt2][tt], 0, 0, 0);
            }
        }
        if (w < 2) {
            #pragma unroll
            for (int jt2 = 0; jt2 < 2; ++jt2) {
                int j = w * 32 + jt2 * 16 + lr;
                float bias = mb1[j];
                #pragma unroll
                for (int tt = 0; tt < 4; ++tt)
                    #pragma unroll
                    for (int r = 0; r < 4; ++r) {
                        int t = tt * 16 + lk * 4 + r;
                        msgl[t * 68 + j] = acc[jt2][tt][r] + bias;
                    }
            }
        } else {
            #pragma unroll
            for (int jt2 = 0; jt2 < 2; ++jt2) {
                int j = wb * 32 + jt2 * 16 + lr;
                float bias = gb0[j];
                #pragma unroll
                for (int tt = 0; tt < 4; ++tt)
                    #pragma unroll
                    for (int r = 0; r < 4; ++r) {
                        int t = tt * 16 + lk * 4 + r;
                        ghl[t * 72 + j] = f2bf(gelu_exact(acc[jt2][tt][r] + bias));
                    }
            }
        }
    }
    __syncthreads();

    // ---- gate: 4 lanes per token, shuffle combine ----
    {
        int t = tid >> 2, q = tid & 3;
        float p = 0.f;
        #pragma unroll
        for (int u = 0; u < 16; ++u) {
            int j = q * 16 + u;
            p += bf2f(ghl[t * 72 + j]) * gw1[j];
        }
        p += __shfl_xor(p, 1, 64);
        p += __shfl_xor(p, 2, 64);
        if (q == 0) gatel[t] = 1.0f / (1.0f + expf(-(p + gb1[0])));
    }
    __syncthreads();

    // ---- scatter gated msg ----
    float* inc = ws + OFF_INC;
    #pragma unroll
    for (int i = tid; i < 64 * D; i += 256) {
        int t = i >> 6, d = i & 63;
        atomicAdd(&inc[((size_t)(b * NSLOT + slotl[t])) * D + d], msgl[t * 68 + d] * gatel[t]);
    }
}

// ---------------- update kernel: bf16 MFMA slot MLP + residual + layernorm ----------------
__global__ __launch_bounds__(256) void update_kernel(
    const float* __restrict__ S,
    const float* __restrict__ ub0, const float* __restrict__ ub1,
    const float* __restrict__ ln_w, const float* __restrict__ ln_b,
    const float* __restrict__ ws, float* __restrict__ out)
{
    __shared__ __align__(16) unsigned short rowl[32 * 136];
    __shared__ __align__(16) unsigned short uul[32 * 136];
    __shared__ float s32[32][69];
    __shared__ float dl[32][69];
    __shared__ float mu_s[32], rs_s[32];

    const int r0  = blockIdx.x * 32;   // flat over B*N
    const int tid = threadIdx.x;

    for (int idx = tid; idx < 32 * D; idx += 256) {
        int t = idx >> 6, d = idx & 63;
        size_t g = (size_t)(r0 + t) * D + d;
        float sv = S[g], iv = ws[OFF_INC + g];
        s32[t][d] = sv;
        rowl[t * 136 + d]     = f2bf(sv);
        rowl[t * 136 + D + d] = f2bf(iv);
    }
    __syncthreads();

    const int w  = tid >> 6;
    const int l  = tid & 63;
    const int lr = l & 15;
    const int lk = l >> 4;
    const unsigned short* wsu = (const unsigned short*)ws;

    // ---- U1: u = gelu(upd_in @ uw0^T + ub0), wave w -> col-tiles {2w, 2w+1} ----
    {
        f32x4 acc[2][2];
        #pragma unroll
        for (int c2 = 0; c2 < 2; ++c2) { acc[c2][0] = (f32x4){0.f,0.f,0.f,0.f}; acc[c2][1] = (f32x4){0.f,0.f,0.f,0.f}; }
        for (int ks = 0; ks < 4; ++ks) {
            short8 a[2];
            #pragma unroll
            for (int tt = 0; tt < 2; ++tt)
                a[tt] = *(const short8*)&rowl[(tt * 16 + lr) * 136 + (ks * 4 + lk) * 8];
            #pragma unroll
            for (int c2 = 0; c2 < 2; ++c2) {
                int jt = w * 2 + c2;
                short8 bb = *(const short8*)&wsu[OFF_UW0B * 2 + ((jt * 4 + ks) * 64 + l) * 8];
                #pragma unroll
                for (int tt = 0; tt < 2; ++tt)
                    acc[c2][tt] = __builtin_amdgcn_mfma_f32_16x16x32_bf16(a[tt], bb, acc[c2][tt], 0, 0, 0);
            }
        }
        #pragma unroll
        for (int c2 = 0; c2 < 2; ++c2) {
            int j = (w * 2 + c2) * 16 + lr;
            float bias = ub0[j];
            #pragma unroll
            for (int tt = 0; tt < 2; ++tt)
                #pragma unroll
                for (int r = 0; r < 4; ++r) {
                    int t = tt * 16 + lk * 4 + r;
                    uul[t * 136 + j] = f2bf(gelu_exact(acc[c2][tt][r] + bias));
                }
        }
    }
    __syncthreads();

    // ---- U2: delta = u @ uw1^T + ub1, wave w -> col-tile w ----
    {
        f32x4 acc[2];
        acc[0] = (f32x4){0.f,0.f,0.f,0.f}; acc[1] = (f32x4){0.f,0.f,0.f,0.f};
        for (int ks = 0; ks < 4; ++ks) {
            short8 a[2];
            #pragma unroll
            for (int tt = 0; tt < 2; ++tt)
                a[tt] = *(const short8*)&uul[(tt * 16 + lr) * 136 + (ks * 4 + lk) * 8];
            short8 bb = *(const short8*)&wsu[OFF_UW1B * 2 + ((w * 4 + ks) * 64 + l) * 8];
            #pragma unroll
            for (int tt = 0; tt < 2; ++tt)
                acc[tt] = __builtin_amdgcn_mfma_f32_16x16x32_bf16(a[tt], bb, acc[tt], 0, 0, 0);
        }
        int j = w * 16 + lr;
        float bias = ub1[j];
        #pragma unroll
        for (int tt = 0; tt < 2; ++tt)
            #pragma unroll
            for (int r = 0; r < 4; ++r) {
                int t = tt * 16 + lk * 4 + r;
                dl[t][j] = acc[tt][r] + bias;
            }
    }
    __syncthreads();

    if (tid < 32) {
        int t = tid;
        float m = 0.f;
        for (int d = 0; d < D; ++d) m += s32[t][d] + dl[t][d];
        m *= (1.0f / D);
        float v = 0.f;
        for (int d = 0; d < D; ++d) { float dd = s32[t][d] + dl[t][d] - m; v += dd * dd; }
        v *= (1.0f / D);
        mu_s[t] = m;
        rs_s[t] = rsqrtf(v + EPS);
    }
    __syncthreads();

    for (int idx = tid; idx < 32 * D; idx += 256) {
        int t = idx >> 6, d = idx & 63;
        out[(size_t)(r0 + t) * D + d] =
            (s32[t][d] + dl[t][d] - mu_s[t]) * rs_s[t] * ln_w[d] + ln_b[d];
    }
}

extern "C" void kernel_launch(void* const* d_in, const int* in_sizes, int n_in,
                              void* d_out, int out_size, void* d_ws, size_t ws_size,
                              hipStream_t stream)
{
    const float* X    = (const float*)d_in[0];
    const float* S    = (const float*)d_in[1];
    const float* Wg   = (const float*)d_in[2];
    const float* Ws   = (const float*)d_in[3];
    const float* mw0  = (const float*)d_in[4];
    const float* mb0  = (const float*)d_in[5];
    const float* mw1  = (const float*)d_in[6];
    const float* mb1  = (const float*)d_in[7];
    const float* gw0  = (const float*)d_in[8];
    const float* gb0  = (const float*)d_in[9];
    const float* gw1  = (const float*)d_in[10];
    const float* gb1  = (const float*)d_in[11];
    const float* uw0  = (const float*)d_in[12];
    const float* ub0  = (const float*)d_in[13];
    const float* uw1  = (const float*)d_in[14];
    const float* ub1  = (const float*)d_in[15];
    const float* ln_w = (const float*)d_in[16];
    const float* ln_b = (const float*)d_in[17];

    float* ws  = (float*)d_ws;
    float* out = (float*)d_out;

    hipMemsetAsync(ws + OFF_INC, 0, (size_t)B * NSLOT * D * sizeof(float), stream);

    prep_kernel<<<432, 256, 0, stream>>>(S, Wg, Ws, mw0, mw1, gw0, uw0, uw1, ws);
    token_kernel<<<(B * L) / 64, 256, 0, stream>>>(X, mb0, mb1, gb0, gw1, gb1, ws);
    update_kernel<<<(B * NSLOT) / 32, 256, 0, stream>>>(S, ub0, ub1, ln_w, ln_b, ws, out);
}

// Round 12
// 151.040 us; speedup vs baseline: 1.4241x; 1.4241x over previous
//
#include <hip/hip_runtime.h>
#include <math.h>

#define B 8
#define L 4096
#define D 64
#define TD 128          // 2*D
#define G 64
#define KS 16
#define NSLOT 1024      // G*KS
#define EPS 1e-5f

// ---- workspace layout (float offsets) ----
#define OFF_PART 0        // 8192 fp32 ssum partials [b][c][d], c = 16 chunks of 64 slots
#define OFF_WGT  8192     // 8192 fp32 [k][g] 128x64
#define OFF_WST  16384    // 2048 fp32 [k][s] 128x16
#define OFF_MW0B 18432    // 16384 bf16 (8192 f)  MFMA B-frag
#define OFF_MW1B 26624    // 8192 bf16 (4096 f)
#define OFF_GW0B 30720    // 8192 bf16 (4096 f)
#define OFF_UW0B 34816    // 16384 bf16 (8192 f)
#define OFF_UW1B 43008    // 8192 bf16 (4096 f)
#define OFF_SLOT 47104    // 32768 ints
#define OFF_INC  79872    // 524288 fp32 incoming [B][N][D]
// total 604160 floats ≈ 2.42 MB

typedef __attribute__((ext_vector_type(8))) short short8;
typedef __attribute__((ext_vector_type(4))) float f32x4;

__device__ __forceinline__ float gelu_exact(float x) {
    return 0.5f * x * (1.0f + erff(x * 0.70710678118654752f));
}

__device__ __forceinline__ unsigned short f2bf(float f) {
    unsigned u = __float_as_uint(f);
    u += 0x7FFFu + ((u >> 16) & 1u);        // round-to-nearest-even
    return (unsigned short)(u >> 16);
}

__device__ __forceinline__ float bf2f(unsigned short u) {
    unsigned v = ((unsigned)u) << 16;
    return __uint_as_float(v);
}

// B-fragment mapping for 16x16x32 bf16 MFMA, 16-col tiles, K=128.
__device__ __forceinline__ void fragmap(int r, int& j, int& k) {
    int e = r & 7, l = (r >> 3) & 63, ks = (r >> 9) & 3, jt = r >> 11;
    j = jt * 16 + (l & 15);
    k = ks * 32 + (l >> 4) * 8 + e;
}

// ---------------- prep: weight packs + ssum partials ----------------
__global__ __launch_bounds__(256) void prep_kernel(
    const float* __restrict__ S, const float* __restrict__ Wg,
    const float* __restrict__ Ws, const float* __restrict__ mw0,
    const float* __restrict__ mw1, const float* __restrict__ gw0,
    const float* __restrict__ uw0, const float* __restrict__ uw1,
    float* __restrict__ ws)
{
    int blk = blockIdx.x;
    if (blk < 264) {
        int idx = blk * 256 + threadIdx.x;   // [0, 67584)
        unsigned short* wsu = (unsigned short*)ws;
        int j, k;
        if (idx < 8192) {                        // WGT fp32 [k][g]
            int kk = idx >> 6, g = idx & 63;
            ws[OFF_WGT + idx] = Wg[g * TD + kk];
        } else if (idx < 10240) {                // WST fp32 [k][s]
            int r = idx - 8192; int kk = r >> 4, s = r & 15;
            ws[OFF_WST + r] = Ws[s * TD + kk];
        } else if (idx < 26624) {                // MW0B
            int r = idx - 10240; fragmap(r, j, k);
            wsu[OFF_MW0B * 2 + r] = f2bf(mw0[j * TD + k]);
        } else if (idx < 34816) {                // MW1B
            int r = idx - 26624; fragmap(r, j, k);
            wsu[OFF_MW1B * 2 + r] = f2bf(mw1[j * TD + k]);
        } else if (idx < 43008) {                // GW0B
            int r = idx - 34816; fragmap(r, j, k);
            wsu[OFF_GW0B * 2 + r] = f2bf(gw0[j * TD + k]);
        } else if (idx < 59392) {                // UW0B
            int r = idx - 43008; fragmap(r, j, k);
            wsu[OFF_UW0B * 2 + r] = f2bf(uw0[j * TD + k]);
        } else if (idx < 67584) {                // UW1B
            int r = idx - 59392; fragmap(r, j, k);
            wsu[OFF_UW1B * 2 + r] = f2bf(uw1[j * TD + k]);
        }
    } else {
        // ssum partials: block per (b, chunk of 64 slots); serial in-chunk order
        int pb = blk - 264;              // [0,128)
        int b = pb >> 4, c = pb & 15;
        int d = threadIdx.x;
        if (d < D) {
            const float* Sp = S + ((size_t)(b * NSLOT + c * 64)) * D + d;
            float acc = 0.f;
            #pragma unroll 16
            for (int u = 0; u < 64; ++u) acc += Sp[(size_t)u * D];
            ws[OFF_PART + pb * 64 + d] = acc;
        }
    }
}

// ---------------- routing: exact fp32 logits, throughput-shaped + argmax ----------------
// 64 tokens/block, 128 threads. Thread = (token-group g of 4, logit-group q of 8).
// Per thread: 4 tokens x (8 group-logits + 2 slot-logits), k-serial fmaf chains
// (same accumulation order as the round-2/4 passing fp32 code).
__global__ __launch_bounds__(128) void routing_kernel(
    const float* __restrict__ X, float* __restrict__ ws)
{
    __shared__ float Wg_l[128][64];   // 32 KB
    __shared__ float Ws_l[128][16];   // 8 KB
    __shared__ float xs_l[128][64];   // 32 KB  [k][t]
    __shared__ float ssf[64];

    const int tid  = threadIdx.x;
    const int tok0 = blockIdx.x * 64;
    const int b    = tok0 >> 12;      // / L

    // ssum from partials (fixed chunk order -> identical bits in routing & msg)
    if (tid < 64) {
        float a = 0.f;
        #pragma unroll
        for (int c = 0; c < 16; ++c) a += ws[OFF_PART + (b * 16 + c) * 64 + tid];
        ssf[tid] = a * (1.0f / NSLOT);
    }
    __syncthreads();

    // stage weights (coalesced float4 copies from L2)
    {
        float* wgf = &Wg_l[0][0];
        for (int i = tid; i < 2048; i += 128)
            *(float4*)(wgf + i * 4) = *(const float4*)(ws + OFF_WGT + i * 4);
        float* wsf = &Ws_l[0][0];
        for (int i = tid; i < 512; i += 128)
            *(float4*)(wsf + i * 4) = *(const float4*)(ws + OFF_WST + i * 4);
    }
    // stage XS tile [k][t]: rows 0..63 = X, rows 64..127 = ssum broadcast
    for (int idx = tid; idx < 8192; idx += 128) {
        int i = idx & 63, dd = idx >> 6;
        xs_l[dd][i] = (dd < 64) ? X[(size_t)(tok0 + i) * D + dd] : ssf[dd - 64];
    }
    __syncthreads();

    const int g = tid >> 3;   // token group: tokens g*4 .. g*4+3
    const int q = tid & 7;    // logit group: Wg cols q*8..q*8+7, Ws cols q*2..q*2+1

    float accg[4][8];
    float accs[4][2];
    #pragma unroll
    for (int t = 0; t < 4; ++t) {
        #pragma unroll
        for (int u = 0; u < 8; ++u) accg[t][u] = 0.f;
        accs[t][0] = 0.f; accs[t][1] = 0.f;
    }

    #pragma unroll 2
    for (int k = 0; k < 128; ++k) {
        float4 xv = *(const float4*)&xs_l[k][g * 4];
        float4 w0 = *(const float4*)&Wg_l[k][q * 8];
        float4 w1 = *(const float4*)&Wg_l[k][q * 8 + 4];
        float2 wv = *(const float2*)&Ws_l[k][q * 2];
        float xarr[4] = {xv.x, xv.y, xv.z, xv.w};
        #pragma unroll
        for (int t = 0; t < 4; ++t) {
            float x = xarr[t];
            accg[t][0] = fmaf(x, w0.x, accg[t][0]);
            accg[t][1] = fmaf(x, w0.y, accg[t][1]);
            accg[t][2] = fmaf(x, w0.z, accg[t][2]);
            accg[t][3] = fmaf(x, w0.w, accg[t][3]);
            accg[t][4] = fmaf(x, w1.x, accg[t][4]);
            accg[t][5] = fmaf(x, w1.y, accg[t][5]);
            accg[t][6] = fmaf(x, w1.z, accg[t][6]);
            accg[t][7] = fmaf(x, w1.w, accg[t][7]);
            accs[t][0] = fmaf(x, wv.x, accs[t][0]);
            accs[t][1] = fmaf(x, wv.y, accs[t][1]);
        }
    }

    // argmax: local first-max (ties -> smaller u), then 8-lane reduce (ties -> smaller j)
    #pragma unroll
    for (int t = 0; t < 4; ++t) {
        float bv = accg[t][0]; int bj = q * 8;
        #pragma unroll
        for (int u = 1; u < 8; ++u) {
            float v = accg[t][u];
            if (v > bv) { bv = v; bj = q * 8 + u; }
        }
        #pragma unroll
        for (int off = 4; off >= 1; off >>= 1) {
            float ov = __shfl_xor(bv, off, 64);
            int   oj = __shfl_xor(bj, off, 64);
            if (ov > bv || (ov == bv && oj < bj)) { bv = ov; bj = oj; }
        }
        float sv = accs[t][0]; int sj = q * 2;
        if (accs[t][1] > sv) { sv = accs[t][1]; sj = q * 2 + 1; }
        #pragma unroll
        for (int off = 4; off >= 1; off >>= 1) {
            float ov = __shfl_xor(sv, off, 64);
            int   oj = __shfl_xor(sj, off, 64);
            if (ov > sv || (ov == sv && oj < sj)) { sv = ov; sj = oj; }
        }
        if (q == 0) ((int*)(ws + OFF_SLOT))[tok0 + g * 4 + t] = bj * KS + sj;
    }
}

// ---------------- msg kernel: bf16 MFMA MLPs + gate + scatter (round-4 proven) ----------------
__global__ __launch_bounds__(256) void msg_kernel(
    const float* __restrict__ X,
    const float* __restrict__ mb0, const float* __restrict__ mb1,
    const float* __restrict__ gb0, const float* __restrict__ gw1,
    const float* __restrict__ gb1, float* __restrict__ ws)
{
    // padded stride 136 bf16 elems (272 B) -> benign 2-way LDS conflicts on frag reads
    __shared__ __align__(16) unsigned short xsl[64 * 136];
    __shared__ __align__(16) unsigned short hhl[64 * 136];
    __shared__ float msgl[64 * 68];
    __shared__ float ghl[64 * 68];
    __shared__ float gatel[64];
    __shared__ int   slotl[64];
    __shared__ float ssf[64];

    const int tid  = threadIdx.x;
    const int tok0 = blockIdx.x * 64;
    const int b    = tok0 >> 12;      // / L

    if (tid < 64) slotl[tid] = ((const int*)(ws + OFF_SLOT))[tok0 + tid];
    // ssum from partials (identical order/bits as routing_kernel)
    if (tid >= 64 && tid < 128) {
        int d = tid - 64;
        float a = 0.f;
        #pragma unroll
        for (int c = 0; c < 16; ++c) a += ws[OFF_PART + (b * 16 + c) * 64 + d];
        ssf[d] = a * (1.0f / NSLOT);
    }
    __syncthreads();

    // ---- stage XS as bf16 ----
    {
        int t = tid >> 2, q = tid & 3;
        unsigned short tmp[32];
        if (q < 2) {
            const float* Xp = X + (size_t)(tok0 + t) * D + q * 32;
            #pragma unroll
            for (int u = 0; u < 8; ++u) {
                float4 v = *(const float4*)(Xp + u * 4);
                tmp[u*4+0] = f2bf(v.x); tmp[u*4+1] = f2bf(v.y);
                tmp[u*4+2] = f2bf(v.z); tmp[u*4+3] = f2bf(v.w);
            }
        } else {
            const float* Sp = ssf + (q - 2) * 32;
            #pragma unroll
            for (int u = 0; u < 32; ++u) tmp[u] = f2bf(Sp[u]);
        }
        #pragma unroll
        for (int s = 0; s < 4; ++s)
            *(short8*)&xsl[t * 136 + (q * 4 + s) * 8] = *(const short8*)&tmp[s * 8];
    }
    __syncthreads();

    const int w  = tid >> 6;
    const int l  = tid & 63;
    const int lr = l & 15;
    const int lk = l >> 4;
    const unsigned short* wsu = (const unsigned short*)ws;

    // ---- GEMM1: H = gelu(XS @ mw0^T + mb0), wave w owns cols [w*32, w*32+32) ----
    {
        f32x4 acc[2][4];
        #pragma unroll
        for (int a_ = 0; a_ < 2; ++a_)
            #pragma unroll
            for (int b_ = 0; b_ < 4; ++b_) acc[a_][b_] = (f32x4){0.f, 0.f, 0.f, 0.f};

        for (int ks = 0; ks < 4; ++ks) {
            short8 a[4];
            #pragma unroll
            for (int tt = 0; tt < 4; ++tt)
                a[tt] = *(const short8*)&xsl[(tt * 16 + lr) * 136 + (ks * 4 + lk) * 8];
            #pragma unroll
            for (int jt2 = 0; jt2 < 2; ++jt2) {
                int jt = w * 2 + jt2;
                short8 bb = *(const short8*)&wsu[OFF_MW0B * 2 + ((jt * 4 + ks) * 64 + l) * 8];
                #pragma unroll
                for (int tt = 0; tt < 4; ++tt)
                    acc[jt2][tt] = __builtin_amdgcn_mfma_f32_16x16x32_bf16(a[tt], bb, acc[jt2][tt], 0, 0, 0);
            }
        }
        #pragma unroll
        for (int jt2 = 0; jt2 < 2; ++jt2) {
            int j = w * 32 + jt2 * 16 + lr;
            float bias = mb0[j];
            #pragma unroll
            for (int tt = 0; tt < 4; ++tt) {
                #pragma unroll
                for (int r = 0; r < 4; ++r) {
                    int t = tt * 16 + lk * 4 + r;
                    hhl[t * 136 + j] = f2bf(gelu_exact(acc[jt2][tt][r] + bias));
                }
            }
        }
    }
    __syncthreads();

    // ---- GEMM2: waves 0,1: msg = H @ mw1^T + mb1 ; waves 2,3: gh = gelu(XS @ gw0^T + gb0) ----
    {
        f32x4 acc[2][4];
        #pragma unroll
        for (int a_ = 0; a_ < 2; ++a_)
            #pragma unroll
            for (int b_ = 0; b_ < 4; ++b_) acc[a_][b_] = (f32x4){0.f, 0.f, 0.f, 0.f};

        const unsigned short* srcA = (w < 2) ? hhl : xsl;
        const int wb   = (w < 2) ? w : (w - 2);
        const int boff = (w < 2) ? OFF_MW1B * 2 : OFF_GW0B * 2;

        for (int ks = 0; ks < 4; ++ks) {
            short8 a[4];
            #pragma unroll
            for (int tt = 0; tt < 4; ++tt)
                a[tt] = *(const short8*)&srcA[(tt * 16 + lr) * 136 + (ks * 4 + lk) * 8];
            #pragma unroll
            for (int jt2 = 0; jt2 < 2; ++jt2) {
                int jt = wb * 2 + jt2;
                short8 bb = *(const short8*)&wsu[boff + ((jt * 4 + ks) * 64 + l) * 8];
                #pragma unroll
                for (int tt = 0; tt < 4; ++tt)
                    acc[jt2][tt] = __builtin_amdgcn_mfma_f32_16x16x32_bf16(a[tt], bb, acc[jt2][tt], 0, 0, 0);
            }
        }
        if (w < 2) {
            #pragma unroll
            for (int jt2 = 0; jt2 < 2; ++jt2) {
                int j = w * 32 + jt2 * 16 + lr;
                float bias = mb1[j];
                #pragma unroll
                for (int tt = 0; tt < 4; ++tt)
                    #pragma unroll
                    for (int r = 0; r < 4; ++r) {
                        int t = tt * 16 + lk * 4 + r;
                        msgl[t * 68 + j] = acc[jt2][tt][r] + bias;
                    }
            }
        } else {
            #pragma unroll
            for (int jt2 = 0; jt2 < 2; ++jt2) {
                int j = wb * 32 + jt2 * 16 + lr;
                float bias = gb0[j];
                #pragma unroll
                for (int tt = 0; tt < 4; ++tt)
                    #pragma unroll
                    for (int r = 0; r < 4; ++r) {
                        int t = tt * 16 + lk * 4 + r;
                        ghl[t * 68 + j] = gelu_exact(acc[jt2][tt][r] + bias);
                    }
            }
        }
    }
    __syncthreads();

    // ---- gate scalar per token ----
    if (tid < 64) {
        float acc = gb1[0];
        for (int jj = 0; jj < D; ++jj) acc += ghl[tid * 68 + jj] * gw1[jj];
        gatel[tid] = 1.0f / (1.0f + expf(-acc));
    }
    __syncthreads();

    // ---- scatter gated msg ----
    float* inc = ws + OFF_INC;
    #pragma unroll
    for (int i = tid; i < 64 * D; i += 256) {
        int t = i >> 6, d = i & 63;
        atomicAdd(&inc[((size_t)(b * NSLOT + slotl[t])) * D + d], msgl[t * 68 + d] * gatel[t]);
    }
}

// ---------------- update kernel: bf16 MFMA slot MLP + residual + layernorm ----------------
__global__ __launch_bounds__(256) void update_kernel(
    const float* __restrict__ S,
    const float* __restrict__ ub0, const float* __restrict__ ub1,
    const float* __restrict__ ln_w, const float* __restrict__ ln_b,
    const float* __restrict__ ws, float* __restrict__ out)
{
    __shared__ __align__(16) unsigned short rowl[32 * 136];
    __shared__ __align__(16) unsigned short uul[32 * 136];
    __shared__ float s32[32][69];
    __shared__ float dl[32][69];
    __shared__ float mu_s[32], rs_s[32];

    const int r0  = blockIdx.x * 32;   // flat over B*N
    const int tid = threadIdx.x;

    for (int idx = tid; idx < 32 * D; idx += 256) {
        int t = idx >> 6, d = idx & 63;
        size_t g = (size_t)(r0 + t) * D + d;
        float sv = S[g], iv = ws[OFF_INC + g];
        s32[t][d] = sv;
        rowl[t * 136 + d]     = f2bf(sv);
        rowl[t * 136 + D + d] = f2bf(iv);
    }
    __syncthreads();

    const int w  = tid >> 6;
    const int l  = tid & 63;
    const int lr = l & 15;
    const int lk = l >> 4;
    const unsigned short* wsu = (const unsigned short*)ws;

    // ---- U1: u = gelu(upd_in @ uw0^T + ub0), wave w -> col-tiles {2w, 2w+1} ----
    {
        f32x4 acc[2][2];
        #pragma unroll
        for (int c2 = 0; c2 < 2; ++c2) { acc[c2][0] = (f32x4){0.f,0.f,0.f,0.f}; acc[c2][1] = (f32x4){0.f,0.f,0.f,0.f}; }
        for (int ks = 0; ks < 4; ++ks) {
            short8 a[2];
            #pragma unroll
            for (int tt = 0; tt < 2; ++tt)
                a[tt] = *(const short8*)&rowl[(tt * 16 + lr) * 136 + (ks * 4 + lk) * 8];
            #pragma unroll
            for (int c2 = 0; c2 < 2; ++c2) {
                int jt = w * 2 + c2;
                short8 bb = *(const short8*)&wsu[OFF_UW0B * 2 + ((jt * 4 + ks) * 64 + l) * 8];
                #pragma unroll
                for (int tt = 0; tt < 2; ++tt)
                    acc[c2][tt] = __builtin_amdgcn_mfma_f32_16x16x32_bf16(a[tt], bb, acc[c2][tt], 0, 0, 0);
            }
        }
        #pragma unroll
        for (int c2 = 0; c2 < 2; ++c2) {
            int j = (w * 2 + c2) * 16 + lr;
            float bias = ub0[j];
            #pragma unroll
            for (int tt = 0; tt < 2; ++tt)
                #pragma unroll
                for (int r = 0; r < 4; ++r) {
                    int t = tt * 16 + lk * 4 + r;
                    uul[t * 136 + j] = f2bf(gelu_exact(acc[c2][tt][r] + bias));
                }
        }
    }
    __syncthreads();

    // ---- U2: delta = u @ uw1^T + ub1, wave w -> col-tile w ----
    {
        f32x4 acc[2];
        acc[0] = (f32x4){0.f,0.f,0.f,0.f}; acc[1] = (f32x4){0.f,0.f,0.f,0.f};
        for (int ks = 0; ks < 4; ++ks) {
            short8 a[2];
            #pragma unroll
            for (int tt = 0; tt < 2; ++tt)
                a[tt] = *(const short8*)&uul[(tt * 16 + lr) * 136 + (ks * 4 + lk) * 8];
            short8 bb = *(const short8*)&wsu[OFF_UW1B * 2 + ((w * 4 + ks) * 64 + l) * 8];
            #pragma unroll
            for (int tt = 0; tt < 2; ++tt)
                acc[tt] = __builtin_amdgcn_mfma_f32_16x16x32_bf16(a[tt], bb, acc[tt], 0, 0, 0);
        }
        int j = w * 16 + lr;
        float bias = ub1[j];
        #pragma unroll
        for (int tt = 0; tt < 2; ++tt)
            #pragma unroll
            for (int r = 0; r < 4; ++r) {
                int t = tt * 16 + lk * 4 + r;
                dl[t][j] = acc[tt][r] + bias;
            }
    }
    __syncthreads();

    if (tid < 32) {
        int t = tid;
        float m = 0.f;
        for (int d = 0; d < D; ++d) m += s32[t][d] + dl[t][d];
        m *= (1.0f / D);
        float v = 0.f;
        for (int d = 0; d < D; ++d) { float dd = s32[t][d] + dl[t][d] - m; v += dd * dd; }
        v *= (1.0f / D);
        mu_s[t] = m;
        rs_s[t] = rsqrtf(v + EPS);
    }
    __syncthreads();

    for (int idx = tid; idx < 32 * D; idx += 256) {
        int t = idx >> 6, d = idx & 63;
        out[(size_t)(r0 + t) * D + d] =
            (s32[t][d] + dl[t][d] - mu_s[t]) * rs_s[t] * ln_w[d] + ln_b[d];
    }
}

extern "C" void kernel_launch(void* const* d_in, const int* in_sizes, int n_in,
                              void* d_out, int out_size, void* d_ws, size_t ws_size,
                              hipStream_t stream)
{
    const float* X    = (const float*)d_in[0];
    const float* S    = (const float*)d_in[1];
    const float* Wg   = (const float*)d_in[2];
    const float* Ws   = (const float*)d_in[3];
    const float* mw0  = (const float*)d_in[4];
    const float* mb0  = (const float*)d_in[5];
    const float* mw1  = (const float*)d_in[6];
    const float* mb1  = (const float*)d_in[7];
    const float* gw0  = (const float*)d_in[8];
    const float* gb0  = (const float*)d_in[9];
    const float* gw1  = (const float*)d_in[10];
    const float* gb1  = (const float*)d_in[11];
    const float* uw0  = (const float*)d_in[12];
    const float* ub0  = (const float*)d_in[13];
    const float* uw1  = (const float*)d_in[14];
    const float* ub1  = (const float*)d_in[15];
    const float* ln_w = (const float*)d_in[16];
    const float* ln_b = (const float*)d_in[17];

    float* ws  = (float*)d_ws;
    float* out = (float*)d_out;

    hipMemsetAsync(ws + OFF_INC, 0, (size_t)B * NSLOT * D * sizeof(float), stream);

    prep_kernel<<<392, 256, 0, stream>>>(S, Wg, Ws, mw0, mw1, gw0, uw0, uw1, ws);
    routing_kernel<<<(B * L) / 64, 128, 0, stream>>>(X, ws);
    msg_kernel<<<(B * L) / 64, 256, 0, stream>>>(X, mb0, mb1, gb0, gw1, gb1, ws);
    update_kernel<<<(B * NSLOT) / 32, 256, 0, stream>>>(S, ub0, ub1, ln_w, ln_b, ws, out);
}